// Round 3
// baseline (23891.800 us; speedup 1.0000x reference)
//
#include <hip/hip_runtime.h>
#include <math.h>

#define B_ 64
#define T_ 700
#define U_ 400
#define NF 704                       // flag slots per array (>= T_)

#define FLAG_WORDS (4 * NF)
#define FLAG_BYTES (FLAG_WORDS * 4)

// ---- agent-scope (cross-XCD coherent) helpers: no fences, no L2 invalidation ----
__device__ __forceinline__ float agload(const float* p) {
    return __hip_atomic_load(p, __ATOMIC_RELAXED, __HIP_MEMORY_SCOPE_AGENT);
}
__device__ __forceinline__ void agstore(float* p, float v) {
    __hip_atomic_store(p, v, __ATOMIC_RELAXED, __HIP_MEMORY_SCOPE_AGENT);
}
__device__ __forceinline__ unsigned agloadu(const unsigned* p) {
    return __hip_atomic_load(p, __ATOMIC_RELAXED, __HIP_MEMORY_SCOPE_AGENT);
}

__device__ __forceinline__ float sig_(float v) {
    return __builtin_amdgcn_rcpf(1.f + __expf(-v));
}
__device__ __forceinline__ float tanh_(float v) {
    return 1.f - 2.f * __builtin_amdgcn_rcpf(__expf(2.f * v) + 1.f);
}

__device__ __forceinline__ void waitflag(const unsigned* f, unsigned target) {
    while (agloadu(f) < target) __builtin_amdgcn_s_sleep(1);
}

// 25-group software-pipelined GEMM slice: 5 slots x G elements prefetch (sc1 loads),
// acc[C] += h[k] * wlds[c][wr+k] over this wave's K range of 25*G.
template<int C, int G>
__device__ __forceinline__ void gemm25(const float* __restrict__ hp,
                                       const float* __restrict__ wl,
                                       const int KROW, const int wr,
                                       float* __restrict__ acc)
{
    float pre[5][G];
#pragma unroll
    for (int g = 0; g < 5; ++g)
#pragma unroll
        for (int j = 0; j < G; ++j)
            pre[g][j] = agload(hp + (size_t)(g * G + j) * B_);

#pragma unroll
    for (int o = 0; o < 5; ++o) {
#pragma unroll
        for (int g = 0; g < 5; ++g) {
            const int kk = (o * 5 + g) * G;
            float cur[G];
#pragma unroll
            for (int j = 0; j < G; ++j) cur[j] = pre[g][j];
            if (o < 4) {   // refill this slot for the next outer round (5 groups ahead)
#pragma unroll
                for (int j = 0; j < G; ++j)
                    pre[g][j] = agload(hp + (size_t)(kk + 5 * G + j) * B_);
            }
#pragma unroll
            for (int c = 0; c < C; ++c) {
                const float* wrow = wl + c * KROW + wr + kk;
#pragma unroll
                for (int j4 = 0; j4 < G / 4; ++j4) {
                    const float4 w = *(const float4*)(wrow + j4 * 4);
                    acc[c] += cur[j4 * 4 + 0] * w.x + cur[j4 * 4 + 1] * w.y
                            + cur[j4 * 4 + 2] * w.z + cur[j4 * 4 + 3] * w.w;
                }
            }
        }
    }
}

//  blocks 0..49   : layer 0, 8 units (32 cols), K=400 (Wh0; x*Wx0 added in gate phase)
//  blocks 50..149 : layer 1, 4 units (16 cols), K=800 ([Wx1;Wh1])
//  blocks 150..249: layer 2, 4 units (16 cols), K=800 ([Wx2;Wh2])
//  block 250      : output projection h2 @ Wd + bd
//  Sync: per-(layer,t) monotonic counters, per-wave waits, DEPTH-deep h ring.
template<int DEPTH>
__global__ void __launch_bounds__(256, 1)
lstm_ring(const float* __restrict__ x,
          const float* __restrict__ Wx0,
          const float* __restrict__ Wx1,
          const float* __restrict__ Wx2,
          const float* __restrict__ Wh,
          const float* __restrict__ bias,
          const float* __restrict__ pi,
          const float* __restrict__ pf,
          const float* __restrict__ po,
          const float* __restrict__ Wd,
          const float* __restrict__ bd,
          float* __restrict__ out,
          float* __restrict__ ws)
{
    __shared__ alignas(16) float wlds[12800];        // 51.2 KB [c][K]
    __shared__ alignas(16) float rbuf[4 * 64 * 33];  // 33.8 KB cross-wave reduce

    unsigned* F0 = (unsigned*)ws;
    unsigned* F1 = F0 + NF;
    unsigned* F2 = F1 + NF;
    unsigned* FO = F2 + NF;
    float* hbuf = ws + FLAG_WORDS;   // [3][DEPTH][U][B]

    const int blk  = blockIdx.x;
    const int tid  = threadIdx.x;
    const int lane = tid & 63;
    const int wv   = tid >> 6;

    int layer, u0;
    if      (blk < 50)  { layer = 0; u0 = blk * 8; }
    else if (blk < 150) { layer = 1; u0 = (blk - 50) * 4; }
    else if (blk < 250) { layer = 2; u0 = (blk - 150) * 4; }
    else                { layer = 3; u0 = 0; }

    // ---- one-time weight staging into LDS, transposed to [c][k] ----
    if (layer == 0) {
        for (int i = tid; i < 32 * 400; i += 256) {
            const int c = i & 31, k = i >> 5;
            const int col = ((c >> 3) * U_) + u0 + (c & 7);
            wlds[c * 400 + k] = Wh[(size_t)k * 1600 + col];
        }
    } else if (layer < 3) {
        const float* __restrict__ Wxl = (layer == 1) ? Wx1 : Wx2;
        for (int i = tid; i < 16 * 800; i += 256) {
            const int c = i & 15, k = i >> 4;
            const int col = ((c >> 2) * U_) + u0 + (c & 3);
            wlds[c * 800 + k] = (k < 400)
                ? Wxl[(size_t)k * 1600 + col]
                : Wh[((size_t)layer * U_ + (k - 400)) * 1600 + col];
        }
    } else {
        for (int i = tid; i < 3 * 400; i += 256) {
            const int c = i / 400, k = i - c * 400;
            wlds[c * 400 + k] = Wd[k * 3 + c];
        }
    }
    __syncthreads();

    float cst[2] = {0.f, 0.f};   // per-wave persistent cell state (L0: 2 units/wave)

    for (int t = 0; t < T_; ++t) {
        const int sw = t % DEPTH;                 // slot written this step (also h_{l-1}[t] slot)
        const int sr = (t + DEPTH - 1) % DEPTH;   // own h[t-1] slot (zeros at t=0)

        // ---- per-wave waits: lane 0 spins, wave64 lockstep holds the other lanes ----
        if (lane == 0) {
            if (layer == 0) {
                if (t >= 1) waitflag(F0 + t - 1, 50);
                if (wv == 0 && t >= DEPTH) waitflag(F1 + t - DEPTH, 100);
            } else if (layer == 1) {
                if (wv < 2) waitflag(F0 + t, 50);            // input half h0[t]
                else if (t >= 1) waitflag(F1 + t - 1, 100);  // own half h1[t-1]
                if (wv == 0 && t >= DEPTH) waitflag(F2 + t - DEPTH, 100);
            } else if (layer == 2) {
                if (wv < 2) waitflag(F1 + t, 100);
                else if (t >= 1) waitflag(F2 + t - 1, 100);
                if (wv == 0 && t >= DEPTH) waitflag(FO + t - DEPTH, 1);
            } else {
                waitflag(F2 + t, 100);
            }
        }
        asm volatile("" ::: "memory");   // don't hoist h loads above the flag wait

        if (layer == 0) {
            float acc[32];
#pragma unroll
            for (int c = 0; c < 32; ++c) acc[c] = 0.f;
            const float* hread = hbuf + (size_t)(0 * DEPTH + sr) * U_ * B_;
            gemm25<32, 4>(hread + (size_t)(wv * 100) * B_ + lane, wlds, 400, wv * 100, acc);
#pragma unroll
            for (int c = 0; c < 32; ++c) rbuf[(wv * 64 + lane) * 33 + c] = acc[c];
            __syncthreads();

            const float x0 = x[((size_t)lane * T_ + t) * 3 + 0];
            const float x1 = x[((size_t)lane * T_ + t) * 3 + 1];
            const float x2 = x[((size_t)lane * T_ + t) * 3 + 2];
            float* hw = hbuf + (size_t)(0 * DEPTH + sw) * U_ * B_;
#pragma unroll
            for (int q = 0; q < 2; ++q) {
                const int ul = wv + q * 4;
                const int ug = u0 + ul;
                float z[4];
#pragma unroll
                for (int g = 0; g < 4; ++g) {
                    float s = 0.f;
#pragma unroll
                    for (int w2 = 0; w2 < 4; ++w2) s += rbuf[(w2 * 64 + lane) * 33 + g * 8 + ul];
                    const int col = g * U_ + ug;
                    z[g] = s + bias[col] + x0 * Wx0[col] + x1 * Wx0[1600 + col] + x2 * Wx0[3200 + col];
                }
                const float cp = cst[q];
                const float ig = sig_(z[0] + pi[ug] * cp);
                const float fg = sig_(z[1] + pf[ug] * cp);
                const float cn = fg * cp + ig * tanh_(z[2]);
                const float og = sig_(z[3] + po[ug] * cn);
                cst[q] = cn;
                agstore(hw + (size_t)ug * B_ + lane, og * tanh_(cn));
            }
        } else if (layer < 3) {
            float acc[16];
#pragma unroll
            for (int c = 0; c < 16; ++c) acc[c] = 0.f;
            // waves 0,1: h_{l-1}[t] (slot sw); waves 2,3: h_l[t-1] (slot sr)
            const int srcbuf = (wv < 2) ? ((layer - 1) * DEPTH + sw) : (layer * DEPTH + sr);
            const float* hread = hbuf + (size_t)srcbuf * U_ * B_ + (size_t)((wv & 1) * 200) * B_ + lane;
            gemm25<16, 8>(hread, wlds, 800, wv * 200, acc);
#pragma unroll
            for (int c = 0; c < 16; ++c) rbuf[(wv * 64 + lane) * 33 + c] = acc[c];
            __syncthreads();

            const int ug = u0 + wv;            // one unit per wave
            float z[4];
#pragma unroll
            for (int g = 0; g < 4; ++g) {
                float s = 0.f;
#pragma unroll
                for (int w2 = 0; w2 < 4; ++w2) s += rbuf[(w2 * 64 + lane) * 33 + g * 4 + wv];
                z[g] = s + bias[layer * 1600 + g * U_ + ug];
            }
            const float cp = cst[0];
            const float ig = sig_(z[0] + pi[layer * U_ + ug] * cp);
            const float fg = sig_(z[1] + pf[layer * U_ + ug] * cp);
            const float cn = fg * cp + ig * tanh_(z[2]);
            const float og = sig_(z[3] + po[layer * U_ + ug] * cn);
            cst[0] = cn;
            agstore(hbuf + (size_t)(layer * DEPTH + sw) * U_ * B_ + (size_t)ug * B_ + lane,
                    og * tanh_(cn));
        } else {
            float acc[3] = {0.f, 0.f, 0.f};
            const float* hread = hbuf + (size_t)(2 * DEPTH + sw) * U_ * B_ + (size_t)(wv * 100) * B_ + lane;
            gemm25<3, 4>(hread, wlds, 400, wv * 100, acc);
#pragma unroll
            for (int c = 0; c < 3; ++c) rbuf[(wv * 64 + lane) * 33 + c] = acc[c];
            __syncthreads();
            if (wv == 0) {
                float f0 = 0.f, f1 = 0.f, f2 = 0.f;
#pragma unroll
                for (int w2 = 0; w2 < 4; ++w2) {
                    f0 += rbuf[(w2 * 64 + lane) * 33 + 0];
                    f1 += rbuf[(w2 * 64 + lane) * 33 + 1];
                    f2 += rbuf[(w2 * 64 + lane) * 33 + 2];
                }
                out[((size_t)lane * T_ + t) * 3 + 0] = f0 + bd[0];
                out[((size_t)lane * T_ + t) * 3 + 1] = f1 + bd[1];
                out[((size_t)lane * T_ + t) * 3 + 2] = f2 + bd[2];
            }
        }

        // ---- publish: drain sc1 stores to coherence point, then bump counter ----
        asm volatile("s_waitcnt vmcnt(0)" ::: "memory");
        __syncthreads();
        if (tid == 0) {
            unsigned* f = (layer == 0) ? (F0 + t) : (layer == 1) ? (F1 + t)
                        : (layer == 2) ? (F2 + t) : (FO + t);
            __hip_atomic_fetch_add(f, 1u, __ATOMIC_RELAXED, __HIP_MEMORY_SCOPE_AGENT);
        }
    }
}

extern "C" void kernel_launch(void* const* d_in, const int* in_sizes, int n_in,
                              void* d_out, int out_size, void* d_ws, size_t ws_size,
                              hipStream_t stream) {
    const float* x    = (const float*)d_in[0];
    const float* Wx0  = (const float*)d_in[1];
    const float* Wx1  = (const float*)d_in[2];
    const float* Wx2  = (const float*)d_in[3];
    const float* Wh   = (const float*)d_in[4];
    const float* bias = (const float*)d_in[5];
    const float* pi   = (const float*)d_in[6];
    const float* pf   = (const float*)d_in[7];
    const float* po   = (const float*)d_in[8];
    const float* Wd   = (const float*)d_in[9];
    const float* bd   = (const float*)d_in[10];
    float* out = (float*)d_out;
    float* ws  = (float*)d_ws;

    const size_t need8 = FLAG_BYTES + (size_t)3 * 8 * U_ * B_ * 4;   // ~2.47 MB
    const size_t need2 = FLAG_BYTES + (size_t)3 * 2 * U_ * B_ * 4;   // ~0.63 MB

    void* args[] = { (void*)&x, (void*)&Wx0, (void*)&Wx1, (void*)&Wx2, (void*)&Wh,
                     (void*)&bias, (void*)&pi, (void*)&pf, (void*)&po,
                     (void*)&Wd, (void*)&bd, (void*)&out, (void*)&ws };

    if (ws_size >= need8) {
        hipMemsetAsync(d_ws, 0, need8, stream);
        hipError_t err = hipLaunchCooperativeKernel((void*)lstm_ring<8>, dim3(251), dim3(256),
                                                    args, 0, stream);
        if (err != hipSuccess)
            hipLaunchKernelGGL(lstm_ring<8>, dim3(251), dim3(256), 0, stream,
                               x, Wx0, Wx1, Wx2, Wh, bias, pi, pf, po, Wd, bd, out, ws);
    } else {
        hipMemsetAsync(d_ws, 0, need2, stream);
        hipError_t err = hipLaunchCooperativeKernel((void*)lstm_ring<2>, dim3(251), dim3(256),
                                                    args, 0, stream);
        if (err != hipSuccess)
            hipLaunchKernelGGL(lstm_ring<2>, dim3(251), dim3(256), 0, stream,
                               x, Wx0, Wx1, Wx2, Wh, bias, pi, pf, po, Wd, bd, out, ws);
    }
}

// Round 4
// 20212.956 us; speedup vs baseline: 1.1820x; 1.1820x over previous
//
#include <hip/hip_runtime.h>
#include <math.h>

#define B_ 64
#define T_ 700
#define U_ 400
#define NF 704                       // flag slots per array (>= T_ + DEPTH)

// ---- agent-scope (cross-XCD coherent) helpers: no fences, no L2 invalidation ----
__device__ __forceinline__ float agload(const float* p) {
    return __hip_atomic_load(p, __ATOMIC_RELAXED, __HIP_MEMORY_SCOPE_AGENT);
}
__device__ __forceinline__ void agstore(float* p, float v) {
    __hip_atomic_store(p, v, __ATOMIC_RELAXED, __HIP_MEMORY_SCOPE_AGENT);
}
__device__ __forceinline__ unsigned agloadu(const unsigned* p) {
    return __hip_atomic_load(p, __ATOMIC_RELAXED, __HIP_MEMORY_SCOPE_AGENT);
}

__device__ __forceinline__ float sig_(float v) {
    return __builtin_amdgcn_rcpf(1.f + __expf(-v));
}
__device__ __forceinline__ float tanh_(float v) {
    return 1.f - 2.f * __builtin_amdgcn_rcpf(__expf(2.f * v) + 1.f);
}

__device__ __forceinline__ void waitflag(const unsigned* f, unsigned target) {
    while (agloadu(f) < target) __builtin_amdgcn_s_sleep(2);
}

// 25-group software-pipelined GEMM slice: 5 slots x G elements prefetch (sc1 loads),
// acc[C] += h[k] * wlds[c][wr+k] over this wave's K range of 25*G.
template<int C, int G>
__device__ __forceinline__ void gemm25(const float* __restrict__ hp,
                                       const float* __restrict__ wl,
                                       const int KROW, const int wr,
                                       float* __restrict__ acc)
{
    float pre[5][G];
#pragma unroll
    for (int g = 0; g < 5; ++g)
#pragma unroll
        for (int j = 0; j < G; ++j)
            pre[g][j] = agload(hp + (size_t)(g * G + j) * B_);

#pragma unroll
    for (int o = 0; o < 5; ++o) {
#pragma unroll
        for (int g = 0; g < 5; ++g) {
            const int kk = (o * 5 + g) * G;
            float cur[G];
#pragma unroll
            for (int j = 0; j < G; ++j) cur[j] = pre[g][j];
            if (o < 4) {   // refill this slot for the next outer round (5 groups ahead)
#pragma unroll
                for (int j = 0; j < G; ++j)
                    pre[g][j] = agload(hp + (size_t)(kk + 5 * G + j) * B_);
            }
#pragma unroll
            for (int c = 0; c < C; ++c) {
                const float* wrow = wl + c * KROW + wr + kk;
#pragma unroll
                for (int j4 = 0; j4 < G / 4; ++j4) {
                    const float4 w = *(const float4*)(wrow + j4 * 4);
                    acc[c] += cur[j4 * 4 + 0] * w.x + cur[j4 * 4 + 1] * w.y
                            + cur[j4 * 4 + 2] * w.z + cur[j4 * 4 + 3] * w.w;
                }
            }
        }
    }
}

//  blocks 0..49   : layer 0, 8 units (32 cols), K=400 (Wh0; x*Wx0 added in gate phase)
//  blocks 50..149 : layer 1, 4 units (16 cols), K=800 ([Wx1;Wh1])
//  blocks 150..249: layer 2, 4 units (16 cols), K=800 ([Wx2;Wh2])
//  block 250      : output projection h2 @ Wd + bd
//  Sync: per-(layer,t) monotonic counters REPLICATED CP-fold on separate 128B lines
//  (publishers bump all copies fire-and-forget; each poller spins on one copy).
template<int DEPTH, int CP>
__global__ void __launch_bounds__(256, 1)
lstm_ring(const float* __restrict__ x,
          const float* __restrict__ Wx0,
          const float* __restrict__ Wx1,
          const float* __restrict__ Wx2,
          const float* __restrict__ Wh,
          const float* __restrict__ bias,
          const float* __restrict__ pi,
          const float* __restrict__ pf,
          const float* __restrict__ po,
          const float* __restrict__ Wd,
          const float* __restrict__ bd,
          float* __restrict__ out,
          float* __restrict__ ws)
{
    __shared__ alignas(16) float wlds[12800];        // 51.2 KB [c][K]
    __shared__ alignas(16) float rbuf[4 * 64 * 33];  // 33.8 KB cross-wave reduce
    __shared__ alignas(16) float gc[256];            // 1 KB t-invariant gate constants

    const int LW = NF * CP * 32;      // flag words per layer array
    unsigned* F0 = (unsigned*)ws;
    unsigned* F1 = F0 + LW;
    unsigned* F2 = F1 + LW;
    unsigned* FO = F2 + LW;
    float* hbuf = ws + (size_t)4 * LW;   // [3][DEPTH][U][B]

    const int blk  = blockIdx.x;
    const int tid  = threadIdx.x;
    const int lane = tid & 63;
    const int wv   = tid >> 6;
    const int cpi  = (blk + wv) % CP;    // this wave's poll copy

    int layer, u0;
    if      (blk < 50)  { layer = 0; u0 = blk * 8; }
    else if (blk < 150) { layer = 1; u0 = (blk - 50) * 4; }
    else if (blk < 250) { layer = 2; u0 = (blk - 150) * 4; }
    else                { layer = 3; u0 = 0; }

    // ---- one-time weight staging into LDS, transposed to [c][k] ----
    if (layer == 0) {
        for (int i = tid; i < 32 * 400; i += 256) {
            const int c = i & 31, k = i >> 5;
            const int col = ((c >> 3) * U_) + u0 + (c & 7);
            wlds[c * 400 + k] = Wh[(size_t)k * 1600 + col];
        }
        // gate constants: gc[ul*16 + g*4 + {0..3}] = {bias, Wx0r0, Wx0r1, Wx0r2}[col]
        if (tid < 32) {
            const int ul = tid >> 2, g = tid & 3;
            const int col = g * U_ + u0 + ul;
            gc[ul * 16 + g * 4 + 0] = bias[col];
            gc[ul * 16 + g * 4 + 1] = Wx0[col];
            gc[ul * 16 + g * 4 + 2] = Wx0[1600 + col];
            gc[ul * 16 + g * 4 + 3] = Wx0[3200 + col];
        }
        if (tid < 24) {   // gc[128 + ul*3 + j] = {pi,pf,po}[u0+ul]
            const int ul = tid / 3, j = tid - ul * 3;
            const float* pp = (j == 0) ? pi : (j == 1) ? pf : po;
            gc[128 + ul * 3 + j] = pp[u0 + ul];
        }
    } else if (layer < 3) {
        const float* __restrict__ Wxl = (layer == 1) ? Wx1 : Wx2;
        for (int i = tid; i < 16 * 800; i += 256) {
            const int c = i & 15, k = i >> 4;
            const int col = ((c >> 2) * U_) + u0 + (c & 3);
            wlds[c * 800 + k] = (k < 400)
                ? Wxl[(size_t)k * 1600 + col]
                : Wh[((size_t)layer * U_ + (k - 400)) * 1600 + col];
        }
        if (tid < 16) {   // gc[ul*4+g] = bias
            const int ul = tid >> 2, g = tid & 3;
            gc[ul * 4 + g] = bias[layer * 1600 + g * U_ + u0 + ul];
        }
        if (tid < 12) {   // gc[64 + ul*3 + j] = {pi,pf,po}
            const int ul = tid / 3, j = tid - ul * 3;
            const float* pp = (j == 0) ? pi : (j == 1) ? pf : po;
            gc[64 + ul * 3 + j] = pp[layer * U_ + u0 + ul];
        }
    } else {
        for (int i = tid; i < 3 * 400; i += 256) {
            const int c = i / 400, k = i - c * 400;
            wlds[c * 400 + k] = Wd[k * 3 + c];
        }
    }
    __syncthreads();

    float cst[2] = {0.f, 0.f};   // per-wave persistent cell state (L0: 2 units/wave)

    for (int t = 0; t < T_; ++t) {
        const int sw = t % DEPTH;                 // slot written (also h_{l-1}[t] slot)
        const int sr = (t + DEPTH - 1) % DEPTH;   // own h[t-1] slot (zeros at t=0)

        // x loads issue before the spin (independent of flags)
        float x0, x1, x2;
        if (layer == 0) {
            x0 = x[((size_t)lane * T_ + t) * 3 + 0];
            x1 = x[((size_t)lane * T_ + t) * 3 + 1];
            x2 = x[((size_t)lane * T_ + t) * 3 + 2];
        }

        // ---- per-wave waits on this wave's flag copy ----
        if (lane == 0) {
            if (layer == 0) {
                if (t >= 1) waitflag(F0 + ((t - 1) * CP + cpi) * 32, 50);
                if (wv == 0 && t >= DEPTH) waitflag(F1 + ((t - DEPTH) * CP + cpi) * 32, 100);
            } else if (layer == 1) {
                if (wv < 2) waitflag(F0 + (t * CP + cpi) * 32, 50);
                else if (t >= 1) waitflag(F1 + ((t - 1) * CP + cpi) * 32, 100);
                if (wv == 0 && t >= DEPTH) waitflag(F2 + ((t - DEPTH) * CP + cpi) * 32, 100);
            } else if (layer == 2) {
                if (wv < 2) waitflag(F1 + (t * CP + cpi) * 32, 100);
                else if (t >= 1) waitflag(F2 + ((t - 1) * CP + cpi) * 32, 100);
                if (wv == 0 && t >= DEPTH) waitflag(FO + ((t - DEPTH) * CP + cpi) * 32, 1);
            } else {
                waitflag(F2 + (t * CP + cpi) * 32, 100);
            }
        }
        asm volatile("" ::: "memory");   // don't hoist h loads above the flag wait

        if (layer == 0) {
            float acc[32];
#pragma unroll
            for (int c = 0; c < 32; ++c) acc[c] = 0.f;
            const float* hread = hbuf + (size_t)(0 * DEPTH + sr) * U_ * B_;
            gemm25<32, 4>(hread + (size_t)(wv * 100) * B_ + lane, wlds, 400, wv * 100, acc);
#pragma unroll
            for (int c = 0; c < 32; ++c) rbuf[(wv * 64 + lane) * 33 + c] = acc[c];
            __syncthreads();

            float* hw = hbuf + (size_t)(0 * DEPTH + sw) * U_ * B_;
#pragma unroll
            for (int q = 0; q < 2; ++q) {
                const int ul = wv + q * 4;
                const int ug = u0 + ul;
                float z[4];
#pragma unroll
                for (int g = 0; g < 4; ++g) {
                    float s = 0.f;
#pragma unroll
                    for (int w2 = 0; w2 < 4; ++w2) s += rbuf[(w2 * 64 + lane) * 33 + g * 8 + ul];
                    const int gb = ul * 16 + g * 4;
                    z[g] = s + gc[gb + 0] + x0 * gc[gb + 1] + x1 * gc[gb + 2] + x2 * gc[gb + 3];
                }
                const float cp = cst[q];
                const float ig = sig_(z[0] + gc[128 + ul * 3 + 0] * cp);
                const float fg = sig_(z[1] + gc[128 + ul * 3 + 1] * cp);
                const float cn = fg * cp + ig * tanh_(z[2]);
                const float og = sig_(z[3] + gc[128 + ul * 3 + 2] * cn);
                cst[q] = cn;
                agstore(hw + (size_t)ug * B_ + lane, og * tanh_(cn));
            }
        } else if (layer < 3) {
            float acc[16];
#pragma unroll
            for (int c = 0; c < 16; ++c) acc[c] = 0.f;
            // waves 0,1: h_{l-1}[t] (slot sw); waves 2,3: h_l[t-1] (slot sr)
            const int srcbuf = (wv < 2) ? ((layer - 1) * DEPTH + sw) : (layer * DEPTH + sr);
            const float* hread = hbuf + (size_t)srcbuf * U_ * B_ + (size_t)((wv & 1) * 200) * B_ + lane;
            gemm25<16, 8>(hread, wlds, 800, wv * 200, acc);
#pragma unroll
            for (int c = 0; c < 16; ++c) rbuf[(wv * 64 + lane) * 33 + c] = acc[c];
            __syncthreads();

            const int ul = wv;                 // one unit per wave
            float z[4];
#pragma unroll
            for (int g = 0; g < 4; ++g) {
                float s = 0.f;
#pragma unroll
                for (int w2 = 0; w2 < 4; ++w2) s += rbuf[(w2 * 64 + lane) * 33 + g * 4 + ul];
                z[g] = s + gc[ul * 4 + g];
            }
            const float cp = cst[0];
            const float ig = sig_(z[0] + gc[64 + ul * 3 + 0] * cp);
            const float fg = sig_(z[1] + gc[64 + ul * 3 + 1] * cp);
            const float cn = fg * cp + ig * tanh_(z[2]);
            const float og = sig_(z[3] + gc[64 + ul * 3 + 2] * cn);
            cst[0] = cn;
            agstore(hbuf + (size_t)(layer * DEPTH + sw) * U_ * B_ + (size_t)(u0 + ul) * B_ + lane,
                    og * tanh_(cn));
        } else {
            float acc[3] = {0.f, 0.f, 0.f};
            const float* hread = hbuf + (size_t)(2 * DEPTH + sw) * U_ * B_ + (size_t)(wv * 100) * B_ + lane;
            gemm25<3, 4>(hread, wlds, 400, wv * 100, acc);
#pragma unroll
            for (int c = 0; c < 3; ++c) rbuf[(wv * 64 + lane) * 33 + c] = acc[c];
            __syncthreads();
            if (wv == 0) {
                float f0 = 0.f, f1 = 0.f, f2 = 0.f;
#pragma unroll
                for (int w2 = 0; w2 < 4; ++w2) {
                    f0 += rbuf[(w2 * 64 + lane) * 33 + 0];
                    f1 += rbuf[(w2 * 64 + lane) * 33 + 1];
                    f2 += rbuf[(w2 * 64 + lane) * 33 + 2];
                }
                out[((size_t)lane * T_ + t) * 3 + 0] = f0 + bd[0];
                out[((size_t)lane * T_ + t) * 3 + 1] = f1 + bd[1];
                out[((size_t)lane * T_ + t) * 3 + 2] = f2 + bd[2];
            }
        }

        // ---- publish: drain sc1 stores, then bump ALL flag copies (separate lines) ----
        asm volatile("s_waitcnt vmcnt(0)" ::: "memory");
        __syncthreads();
        if (tid < CP) {
            unsigned* f = (layer == 0) ? F0 : (layer == 1) ? F1
                        : (layer == 2) ? F2 : FO;
            __hip_atomic_fetch_add(f + (t * CP + tid) * 32, 1u,
                                   __ATOMIC_RELAXED, __HIP_MEMORY_SCOPE_AGENT);
        }
    }
}

template<int DEPTH, int CP>
static void launch_variant(void* const* d_in, float* out, float* ws, hipStream_t stream) {
    const float* x    = (const float*)d_in[0];
    const float* Wx0  = (const float*)d_in[1];
    const float* Wx1  = (const float*)d_in[2];
    const float* Wx2  = (const float*)d_in[3];
    const float* Wh   = (const float*)d_in[4];
    const float* bias = (const float*)d_in[5];
    const float* pi   = (const float*)d_in[6];
    const float* pf   = (const float*)d_in[7];
    const float* po   = (const float*)d_in[8];
    const float* Wd   = (const float*)d_in[9];
    const float* bd   = (const float*)d_in[10];
    void* args[] = { (void*)&x, (void*)&Wx0, (void*)&Wx1, (void*)&Wx2, (void*)&Wh,
                     (void*)&bias, (void*)&pi, (void*)&pf, (void*)&po,
                     (void*)&Wd, (void*)&bd, (void*)&out, (void*)&ws };
    hipError_t err = hipLaunchCooperativeKernel((void*)lstm_ring<DEPTH, CP>,
                                                dim3(251), dim3(256), args, 0, stream);
    if (err != hipSuccess)
        hipLaunchKernelGGL((lstm_ring<DEPTH, CP>), dim3(251), dim3(256), 0, stream,
                           x, Wx0, Wx1, Wx2, Wh, bias, pi, pf, po, Wd, bd, out, ws);
}

extern "C" void kernel_launch(void* const* d_in, const int* in_sizes, int n_in,
                              void* d_out, int out_size, void* d_ws, size_t ws_size,
                              hipStream_t stream) {
    float* out = (float*)d_out;
    float* ws  = (float*)d_ws;

    auto need = [](int depth, int cp) -> size_t {
        return (size_t)4 * NF * cp * 32 * 4 + (size_t)3 * depth * U_ * B_ * 4;
    };

    if (ws_size >= need(8, 8)) {            // ~5.1 MB
        hipMemsetAsync(d_ws, 0, need(8, 8), stream);
        launch_variant<8, 8>(d_in, out, ws, stream);
    } else if (ws_size >= need(8, 2)) {     // ~3.0 MB
        hipMemsetAsync(d_ws, 0, need(8, 2), stream);
        launch_variant<8, 2>(d_in, out, ws, stream);
    } else {                                 // ~0.93 MB
        hipMemsetAsync(d_ws, 0, need(2, 1), stream);
        launch_variant<2, 1>(d_in, out, ws, stream);
    }
}

// Round 5
// 3336.582 us; speedup vs baseline: 7.1606x; 6.0580x over previous
//
#include <hip/hip_runtime.h>
#include <hip/hip_fp16.h>
#include <math.h>

#define B_ 64
#define T_ 700
#define U_ 400
#define NF 704                        // flag slots per array (>= T_ + DEPTH)
#define CHUNK_DW 256                  // dwords per A-chunk (64 lanes x 4 dwords)
#define FR_LS 13312                   // dwords per (layer,slot): 4 bt x 13 kc x 256

typedef _Float16 half8 __attribute__((ext_vector_type(8)));
typedef float float4v __attribute__((ext_vector_type(4)));

union AFrag { unsigned u[4]; half8 h; };

// ---- agent-scope (cross-XCD coherent) helpers ----
__device__ __forceinline__ unsigned agloadu(const unsigned* p) {
    return __hip_atomic_load(p, __ATOMIC_RELAXED, __HIP_MEMORY_SCOPE_AGENT);
}
__device__ __forceinline__ void agstoreu(unsigned* p, unsigned v) {
    __hip_atomic_store(p, v, __ATOMIC_RELAXED, __HIP_MEMORY_SCOPE_AGENT);
}
__device__ __forceinline__ float sig_(float v) {
    return __builtin_amdgcn_rcpf(1.f + __expf(-v));
}
__device__ __forceinline__ float tanh_(float v) {
    return 1.f - 2.f * __builtin_amdgcn_rcpf(__expf(2.f * v) + 1.f);
}
__device__ __forceinline__ void waitflag(const unsigned* f, unsigned target) {
    while (agloadu(f) < target) __builtin_amdgcn_s_sleep(2);
}
__device__ __forceinline__ unsigned f16u(float v) {
    union { _Float16 f; unsigned short s; } cv; cv.f = (_Float16)v; return (unsigned)cv.s;
}

//  blocks 0..49   : layer 0, 8 units (32 gate-cols = 2 N-tiles), A = h0[t-1] (13 chunks)
//  blocks 50..149 : layer 1, 4 units (16 cols), A = [h0[t] ; h1[t-1]] (13+13 chunks)
//  blocks 150..249: layer 2, 4 units (16 cols), A = [h1[t] ; h2[t-1]]
//  block 250      : output projection h2[t] @ Wd + bd
//  h is exchanged in MFMA A-fragment layout (f16, dword-packed); weights live in
//  LDS in B-fragment order (per-lane-distinct ds_read_b128, no broadcast).
template<int DEPTH, int CP>
__global__ void __launch_bounds__(256, 1)
lstm_mfma(const float* __restrict__ x,
          const float* __restrict__ Wx0,
          const float* __restrict__ Wx1,
          const float* __restrict__ Wx2,
          const float* __restrict__ Wh,
          const float* __restrict__ bias,
          const float* __restrict__ pi,
          const float* __restrict__ pf,
          const float* __restrict__ po,
          const float* __restrict__ Wd,
          const float* __restrict__ bd,
          float* __restrict__ out,
          unsigned* __restrict__ ws)
{
    __shared__ alignas(16) _Float16 wlds[26 * 512];   // 26.6 KB B-frags [ck][lane][8]
    __shared__ alignas(16) float zlds[4 * 528];       // 8.4 KB per-wave z tiles (stride 33)
    __shared__ float gc[160];                          // gate constants

    const int LW = NF * CP * 32;
    unsigned* F0 = ws;
    unsigned* F1 = F0 + LW;
    unsigned* F2 = F1 + LW;
    unsigned* FO = F2 + LW;
    unsigned* frag0 = ws + (size_t)4 * LW;   // [3][DEPTH][FR_LS]

    const int blk  = blockIdx.x;
    const int tid  = threadIdx.x;
    const int lane = tid & 63;
    const int wv   = tid >> 6;
    const int cpi  = (blk + wv) & (CP - 1);

    int layer, u0;
    if      (blk < 50)  { layer = 0; u0 = blk * 8; }
    else if (blk < 150) { layer = 1; u0 = (blk - 50) * 4; }
    else if (blk < 250) { layer = 2; u0 = (blk - 150) * 4; }
    else                { layer = 3; u0 = 0; }

    // ---- one-time: stage weights into LDS in B-fragment order ----
    {
        const float* __restrict__ Wxl = (layer == 1) ? Wx1 : Wx2;
        for (int i = tid; i < 26 * 64; i += 256) {
            const int ln = i & 63, ck = i >> 6;
            const int q = ln >> 4, nn = ln & 15;
            float vals[8];
#pragma unroll
            for (int j = 0; j < 8; ++j) {
                const int kc = ck % 13;
                const int k = kc * 32 + q * 8 + j;
                float v = 0.f;
                if (k < 400) {
                    if (layer == 0) {
                        const int col32 = (ck / 13) * 16 + nn;
                        const int gcol = (col32 >> 3) * U_ + u0 + (col32 & 7);
                        v = Wh[(size_t)k * 1600 + gcol];
                    } else if (layer < 3) {
                        const int gcol = (nn >> 2) * U_ + u0 + (nn & 3);
                        v = (ck >= 13) ? Wh[((size_t)layer * U_ + k) * 1600 + gcol]
                                       : Wxl[(size_t)k * 1600 + gcol];
                    } else {
                        if (ck < 13 && nn < 3) v = Wd[k * 3 + nn];
                    }
                }
                vals[j] = v;
            }
#pragma unroll
            for (int j = 0; j < 8; ++j)
                wlds[ck * 512 + ln * 8 + j] = (_Float16)vals[j];
        }
        // gate constants
        if (layer == 0) {
            if (tid < 128) {
                const int col32 = tid >> 2, comp = tid & 3;
                const int gcol = (col32 >> 3) * U_ + u0 + (col32 & 7);
                gc[tid] = (comp == 0) ? bias[gcol] : Wx0[(size_t)(comp - 1) * 1600 + gcol];
            } else if (tid < 152) {
                const int idx = tid - 128, ul = idx / 3, j = idx - ul * 3;
                const float* pp = (j == 0) ? pi : (j == 1) ? pf : po;
                gc[tid] = pp[u0 + ul];
            }
        } else if (layer < 3) {
            if (tid < 16) {
                gc[tid] = bias[layer * 1600 + (tid >> 2) * U_ + u0 + (tid & 3)];
            } else if (tid < 28) {
                const int idx = tid - 16, ul = idx / 3, j = idx - ul * 3;
                const float* pp = (j == 0) ? pi : (j == 1) ? pf : po;
                gc[tid] = pp[layer * U_ + u0 + ul];
            }
        } else {
            if (tid < 3) gc[tid] = bd[tid];
        }
    }
    __syncthreads();

    const int wvz   = wv * 528;
    const int b_loc = lane & 15;
    const int quad  = lane >> 4;
    float cst[2] = {0.f, 0.f};

    for (int t = 0; t < T_; ++t) {
        const int sw = t % DEPTH;
        const int sr = (t + DEPTH - 1) % DEPTH;

        // x prefetch (L0), independent of flags
        float x0, x1, x2;
        if (layer == 0) {
            const size_t xb = (size_t)(wv * 16 + b_loc) * T_ + t;
            x0 = x[xb * 3 + 0]; x1 = x[xb * 3 + 1]; x2 = x[xb * 3 + 2];
        }

        // ---- wait own-recurrence flag; issue own A-loads ----
        if (lane == 0) {
            if (layer == 0) {
                if (t >= 1) waitflag(F0 + ((t - 1) * CP + cpi) * 32, 50);
                if (wv == 0 && t >= DEPTH) waitflag(F1 + ((t - DEPTH) * CP + cpi) * 32, 100);
            } else if (layer == 1) {
                if (t >= 1) waitflag(F1 + ((t - 1) * CP + cpi) * 32, 100);
            } else if (layer == 2) {
                if (t >= 1) waitflag(F2 + ((t - 1) * CP + cpi) * 32, 100);
            } else {
                waitflag(F2 + (t * CP + cpi) * 32, 100);
            }
        }
        asm volatile("" ::: "memory");

        AFrag aown[13];
        {
            const unsigned* fr = (layer == 3)
                ? frag0 + ((size_t)(2 * DEPTH + sw)) * FR_LS + wv * 3328
                : frag0 + ((size_t)(layer * DEPTH + sr)) * FR_LS + wv * 3328;
#pragma unroll
            for (int kc = 0; kc < 13; ++kc)
#pragma unroll
                for (int d = 0; d < 4; ++d)
                    aown[kc].u[d] = agloadu(fr + kc * 256 + d * 64 + lane);
        }

        // ---- L1/L2: wait input flag (+ lag), issue input A-loads ----
        AFrag ainp[13];
        if (layer == 1 || layer == 2) {
            if (lane == 0) {
                if (layer == 1) {
                    waitflag(F0 + (t * CP + cpi) * 32, 50);
                    if (wv == 0 && t >= DEPTH) waitflag(F2 + ((t - DEPTH) * CP + cpi) * 32, 100);
                } else {
                    waitflag(F1 + (t * CP + cpi) * 32, 100);
                    if (wv == 0 && t >= DEPTH) waitflag(FO + ((t - DEPTH) * CP + cpi) * 32, 1);
                }
            }
            asm volatile("" ::: "memory");
            const unsigned* fr = frag0 + ((size_t)((layer - 1) * DEPTH + sw)) * FR_LS + wv * 3328;
#pragma unroll
            for (int kc = 0; kc < 13; ++kc)
#pragma unroll
                for (int d = 0; d < 4; ++d)
                    ainp[kc].u[d] = agloadu(fr + kc * 256 + d * 64 + lane);
        }

        // ---- MFMA ----
        if (layer == 0) {
            float4v acc0 = {0.f, 0.f, 0.f, 0.f}, acc1 = {0.f, 0.f, 0.f, 0.f};
#pragma unroll
            for (int kc = 0; kc < 13; ++kc) {
                const half8 w0 = *(const half8*)&wlds[kc * 512 + lane * 8];
                const half8 w1 = *(const half8*)&wlds[(13 + kc) * 512 + lane * 8];
                acc0 = __builtin_amdgcn_mfma_f32_16x16x32_f16(aown[kc].h, w0, acc0, 0, 0, 0);
                acc1 = __builtin_amdgcn_mfma_f32_16x16x32_f16(aown[kc].h, w1, acc1, 0, 0, 0);
            }
#pragma unroll
            for (int r = 0; r < 4; ++r) {
                zlds[wvz + (quad * 4 + r) * 33 + b_loc] = acc0[r];
                zlds[wvz + (quad * 4 + r) * 33 + 16 + b_loc] = acc1[r];
            }
        } else if (layer < 3) {
            float4v acc = {0.f, 0.f, 0.f, 0.f};
#pragma unroll
            for (int kc = 0; kc < 13; ++kc) {
                const half8 wA = *(const half8*)&wlds[kc * 512 + lane * 8];          // Wx part
                const half8 wB = *(const half8*)&wlds[(13 + kc) * 512 + lane * 8];   // Wh part
                acc = __builtin_amdgcn_mfma_f32_16x16x32_f16(ainp[kc].h, wA, acc, 0, 0, 0);
                acc = __builtin_amdgcn_mfma_f32_16x16x32_f16(aown[kc].h, wB, acc, 0, 0, 0);
            }
#pragma unroll
            for (int r = 0; r < 4; ++r)
                zlds[wvz + (quad * 4 + r) * 33 + b_loc] = acc[r];
        } else {
            float4v acc = {0.f, 0.f, 0.f, 0.f};
#pragma unroll
            for (int kc = 0; kc < 13; ++kc) {
                const half8 w0 = *(const half8*)&wlds[kc * 512 + lane * 8];
                acc = __builtin_amdgcn_mfma_f32_16x16x32_f16(aown[kc].h, w0, acc, 0, 0, 0);
            }
            if (b_loc < 3) {
#pragma unroll
                for (int r = 0; r < 4; ++r)
                    out[((size_t)(wv * 16 + quad * 4 + r) * T_ + t) * 3 + b_loc] = acc[r] + gc[b_loc];
            }
        }
        __syncthreads();   // z tiles visible for gate remap

        // ---- gates (fp32) + h store in A-fragment layout ----
        if (layer == 0) {
            unsigned* fr_dst = frag0 + ((size_t)(0 * DEPTH + sw)) * FR_LS + wv * 3328;
#pragma unroll
            for (int q = 0; q < 2; ++q) {
                const int ul = q * 4 + quad;
                float z[4];
#pragma unroll
                for (int g = 0; g < 4; ++g) {
                    const int gb = (g * 8 + ul) * 4;
                    z[g] = zlds[wvz + b_loc * 33 + g * 8 + ul]
                         + gc[gb + 0] + x0 * gc[gb + 1] + x1 * gc[gb + 2] + x2 * gc[gb + 3];
                }
                const float cp = cst[q];
                const float ig = sig_(z[0] + gc[128 + ul * 3 + 0] * cp);
                const float fg = sig_(z[1] + gc[128 + ul * 3 + 1] * cp);
                const float cn = fg * cp + ig * tanh_(z[2]);
                const float og = sig_(z[3] + gc[128 + ul * 3 + 2] * cn);
                cst[q] = cn;
                const float hv = og * tanh_(cn);
                const float pv = __shfl_xor(hv, 16, 64);
                if ((quad & 1) == 0) {
                    const unsigned pw_ = f16u(hv) | (f16u(pv) << 16);
                    const int u = u0 + ul;               // even
                    agstoreu(fr_dst + (u >> 5) * 256 + ((u & 7) >> 1) * 64
                                    + ((u >> 3) & 3) * 16 + b_loc, pw_);
                }
            }
        } else if (layer < 3) {
            unsigned* fr_dst = frag0 + ((size_t)(layer * DEPTH + sw)) * FR_LS + wv * 3328;
            const int ul = quad;
            float z[4];
#pragma unroll
            for (int g = 0; g < 4; ++g)
                z[g] = zlds[wvz + b_loc * 33 + g * 4 + ul] + gc[g * 4 + ul];
            const float cp = cst[0];
            const float ig = sig_(z[0] + gc[16 + ul * 3 + 0] * cp);
            const float fg = sig_(z[1] + gc[16 + ul * 3 + 1] * cp);
            const float cn = fg * cp + ig * tanh_(z[2]);
            const float og = sig_(z[3] + gc[16 + ul * 3 + 2] * cn);
            cst[0] = cn;
            const float hv = og * tanh_(cn);
            const float pv = __shfl_xor(hv, 16, 64);
            if ((ul & 1) == 0) {
                const unsigned pw_ = f16u(hv) | (f16u(pv) << 16);
                const int u = u0 + ul;                   // even
                agstoreu(fr_dst + (u >> 5) * 256 + ((u & 7) >> 1) * 64
                                + ((u >> 3) & 3) * 16 + b_loc, pw_);
            }
        }

        // ---- publish: drain stores, then bump replicated flag copies ----
        asm volatile("s_waitcnt vmcnt(0)" ::: "memory");
        __syncthreads();
        if (tid < CP) {
            unsigned* f = (layer == 0) ? F0 : (layer == 1) ? F1
                        : (layer == 2) ? F2 : FO;
            __hip_atomic_fetch_add(f + (t * CP + tid) * 32, 1u,
                                   __ATOMIC_RELAXED, __HIP_MEMORY_SCOPE_AGENT);
        }
    }
}

template<int DEPTH, int CP>
static void launch_variant(void* const* d_in, float* out, unsigned* ws, hipStream_t stream) {
    const float* x    = (const float*)d_in[0];
    const float* Wx0  = (const float*)d_in[1];
    const float* Wx1  = (const float*)d_in[2];
    const float* Wx2  = (const float*)d_in[3];
    const float* Wh   = (const float*)d_in[4];
    const float* bias = (const float*)d_in[5];
    const float* pi   = (const float*)d_in[6];
    const float* pf   = (const float*)d_in[7];
    const float* po   = (const float*)d_in[8];
    const float* Wd   = (const float*)d_in[9];
    const float* bd   = (const float*)d_in[10];
    void* args[] = { (void*)&x, (void*)&Wx0, (void*)&Wx1, (void*)&Wx2, (void*)&Wh,
                     (void*)&bias, (void*)&pi, (void*)&pf, (void*)&po,
                     (void*)&Wd, (void*)&bd, (void*)&out, (void*)&ws };
    hipError_t err = hipLaunchCooperativeKernel((void*)lstm_mfma<DEPTH, CP>,
                                                dim3(251), dim3(256), args, 0, stream);
    if (err != hipSuccess)
        hipLaunchKernelGGL((lstm_mfma<DEPTH, CP>), dim3(251), dim3(256), 0, stream,
                           x, Wx0, Wx1, Wx2, Wh, bias, pi, pf, po, Wd, bd, out, ws);
}

extern "C" void kernel_launch(void* const* d_in, const int* in_sizes, int n_in,
                              void* d_out, int out_size, void* d_ws, size_t ws_size,
                              hipStream_t stream) {
    float* out = (float*)d_out;
    unsigned* ws = (unsigned*)d_ws;

    auto need = [](int depth, int cp) -> size_t {
        return (size_t)4 * NF * cp * 32 * 4 + (size_t)3 * depth * FR_LS * 4;
    };

    if (ws_size >= need(8, 8)) {            // ~4.2 MB
        hipMemsetAsync(d_ws, 0, need(8, 8), stream);
        launch_variant<8, 8>(d_in, out, ws, stream);
    } else if (ws_size >= need(4, 4)) {     // ~2.1 MB
        hipMemsetAsync(d_ws, 0, need(4, 4), stream);
        launch_variant<4, 4>(d_in, out, ws, stream);
    } else {                                 // ~1.0 MB
        hipMemsetAsync(d_ws, 0, need(2, 2), stream);
        launch_variant<2, 2>(d_in, out, ws, stream);
    }
}

// Round 8
// 2844.459 us; speedup vs baseline: 8.3994x; 1.1730x over previous
//
#include <hip/hip_runtime.h>
#include <hip/hip_fp16.h>
#include <math.h>

#define B_ 64
#define T_ 700
#define U_ 400
#define NF 704                        // flag slots per array (>= T_ + DEPTH)
#define FR_LS 13312                   // dwords per (layer,slot): 4 bt x 13 kc x 256

typedef _Float16 half8 __attribute__((ext_vector_type(8)));
typedef float float4v __attribute__((ext_vector_type(4)));

union AFrag { unsigned u[4]; half8 h; };

// ---- agent-scope (cross-XCD coherent) helpers ----
__device__ __forceinline__ unsigned agloadu(const unsigned* p) {
    return __hip_atomic_load(p, __ATOMIC_RELAXED, __HIP_MEMORY_SCOPE_AGENT);
}
__device__ __forceinline__ void agstoreu(unsigned* p, unsigned v) {
    __hip_atomic_store(p, v, __ATOMIC_RELAXED, __HIP_MEMORY_SCOPE_AGENT);
}
__device__ __forceinline__ float sig_(float v) {
    return __builtin_amdgcn_rcpf(1.f + __expf(-v));
}
__device__ __forceinline__ float tanh_(float v) {
    return 1.f - 2.f * __builtin_amdgcn_rcpf(__expf(2.f * v) + 1.f);
}
__device__ __forceinline__ void waitflag(const unsigned* f, unsigned target) {
    while (agloadu(f) < target) __builtin_amdgcn_s_sleep(2);
}
__device__ __forceinline__ unsigned f16u(float v) {
    union { _Float16 f; unsigned short s; } cv; cv.f = (_Float16)v; return (unsigned)cv.s;
}

// Parity-tagged own-edge read: sloppy low-volume probe (1 dword/lane, sleep-backed),
// then batched verify over 13 chunks x 4 dwords. Verify is authoritative; wrap-parity
// is ABA-safe (same wave observed opposite parity at these addresses DEPTH steps ago).
// EVERY dword in the region (incl. K-pad) is rewritten each step — see pad writer.
__device__ __forceinline__ void pollfrag13(const unsigned* __restrict__ base,
                                           const unsigned par,
                                           AFrag* __restrict__ a, const int lane)
{
    {   // probe: 1 dword/lane spread across all 13 chunks (no correctness role)
        const unsigned* pp = base + (lane % 13) * 256 + ((lane * 37) & 255);
        while (!__all((int)(((agloadu(pp) ^ par) & 1u) == 0u)))
            __builtin_amdgcn_s_sleep(3);
    }
    unsigned pend = 0x1FFFu;
    do {
#pragma unroll
        for (int ck = 0; ck < 13; ++ck) if ((pend >> ck) & 1) {
#pragma unroll
            for (int d = 0; d < 4; ++d)
                a[ck].u[d] = agloadu(base + ck * 256 + d * 64 + lane);
        }
#pragma unroll
        for (int ck = 0; ck < 13; ++ck) if ((pend >> ck) & 1) {
            const unsigned m = (a[ck].u[0] ^ par) | (a[ck].u[1] ^ par)
                             | (a[ck].u[2] ^ par) | (a[ck].u[3] ^ par);
            if (__all((int)((m & 1u) == 0u))) pend &= ~(1u << ck);
        }
        if (pend) __builtin_amdgcn_s_sleep(3);
    } while (pend);
}

//  blocks 0..49   : layer 0, 8 units (32 gate-cols), A = h0[t-1]
//  blocks 50..149 : layer 1, 4 units, A = [h0[t] ; h1[t-1]]
//  blocks 150..249: layer 2, 4 units, A = [h1[t] ; h2[t-1]]
//  block 250      : output projection h2[t] @ Wd + bd
//  Own-layer edge: wrap-parity tag in LSB of each packed h dword (direct data poll).
//  Cross-layer input edge + lagged anti-overwrite: replicated flag counters (R5).
//  blk 49/149/249 additionally rewrite the 512 K-pad dwords (u=400..415) of their
//  layer's write slot every step — parity-correct, non-NaN (fixes R6/R7 deadlock).
template<int DEPTH, int CP>
__global__ void __launch_bounds__(256, 1)
lstm_mix(const float* __restrict__ x,
         const float* __restrict__ Wx0,
         const float* __restrict__ Wx1,
         const float* __restrict__ Wx2,
         const float* __restrict__ Wh,
         const float* __restrict__ bias,
         const float* __restrict__ pi,
         const float* __restrict__ pf,
         const float* __restrict__ po,
         const float* __restrict__ Wd,
         const float* __restrict__ bd,
         float* __restrict__ out,
         unsigned* __restrict__ ws)
{
    __shared__ alignas(16) _Float16 wlds[26 * 512];   // 26.6 KB B-frags [ck][lane][8]
    __shared__ alignas(16) float zlds[4 * 528];       // 8.4 KB per-wave z tiles
    __shared__ float gc[160];                          // gate constants

    const int LW = NF * CP * 32;
    unsigned* F0 = ws;
    unsigned* F1 = F0 + LW;
    unsigned* F2 = F1 + LW;
    unsigned* FO = F2 + LW;
    unsigned* frag0 = ws + (size_t)4 * LW;   // [3][DEPTH][FR_LS], init 0xFF (parity 1)

    const int blk  = blockIdx.x;
    const int tid  = threadIdx.x;
    const int lane = tid & 63;
    const int wv   = tid >> 6;
    const int cpi  = (blk + wv) & (CP - 1);

    int layer, u0;
    if      (blk < 50)  { layer = 0; u0 = blk * 8; }
    else if (blk < 150) { layer = 1; u0 = (blk - 50) * 4; }
    else if (blk < 250) { layer = 2; u0 = (blk - 150) * 4; }
    else                { layer = 3; u0 = 0; }

    const bool padw = (blk == 49) || (blk == 149) || (blk == 249);
    // pad dword addresses (2 per thread): kc=12, q in {2,3}, d in 0..3, b_loc 0..15
    int pad_off[2];
    {
        const int i0 = tid, i1 = tid + 256;
        pad_off[0] = (i0 >> 7) * 3328 + 12 * 256 + (((i0 >> 4) & 3) * 64)
                   + (2 + ((i0 >> 6) & 1)) * 16 + (i0 & 15);
        pad_off[1] = (i1 >> 7) * 3328 + 12 * 256 + (((i1 >> 4) & 3) * 64)
                   + (2 + ((i1 >> 6) & 1)) * 16 + (i1 & 15);
    }

    // ---- one-time: stage weights into LDS in B-fragment order ----
    {
        const float* __restrict__ Wxl = (layer == 1) ? Wx1 : Wx2;
        for (int i = tid; i < 26 * 64; i += 256) {
            const int ln = i & 63, ck = i >> 6;
            const int q = ln >> 4, nn = ln & 15;
            float vals[8];
#pragma unroll
            for (int j = 0; j < 8; ++j) {
                const int kc = ck % 13;
                const int k = kc * 32 + q * 8 + j;
                float v = 0.f;
                if (k < 400) {
                    if (layer == 0) {
                        const int col32 = (ck / 13) * 16 + nn;
                        const int gcol = (col32 >> 3) * U_ + u0 + (col32 & 7);
                        v = Wh[(size_t)k * 1600 + gcol];
                    } else if (layer < 3) {
                        const int gcol = (nn >> 2) * U_ + u0 + (nn & 3);
                        v = (ck >= 13) ? Wh[((size_t)layer * U_ + k) * 1600 + gcol]
                                       : Wxl[(size_t)k * 1600 + gcol];
                    } else {
                        if (ck < 13 && nn < 3) v = Wd[k * 3 + nn];
                    }
                }
                vals[j] = v;
            }
#pragma unroll
            for (int j = 0; j < 8; ++j)
                wlds[ck * 512 + ln * 8 + j] = (_Float16)vals[j];
        }
        if (layer == 0) {
            if (tid < 128) {
                const int col32 = tid >> 2, comp = tid & 3;
                const int gcol = (col32 >> 3) * U_ + u0 + (col32 & 7);
                gc[tid] = (comp == 0) ? bias[gcol] : Wx0[(size_t)(comp - 1) * 1600 + gcol];
            } else if (tid < 152) {
                const int idx = tid - 128, ul = idx / 3, j = idx - ul * 3;
                const float* pp = (j == 0) ? pi : (j == 1) ? pf : po;
                gc[tid] = pp[u0 + ul];
            }
        } else if (layer < 3) {
            if (tid < 16) {
                gc[tid] = bias[layer * 1600 + (tid >> 2) * U_ + u0 + (tid & 3)];
            } else if (tid < 28) {
                const int idx = tid - 16, ul = idx / 3, j = idx - ul * 3;
                const float* pp = (j == 0) ? pi : (j == 1) ? pf : po;
                gc[tid] = pp[layer * U_ + u0 + ul];
            }
        } else {
            if (tid < 3) gc[tid] = bd[tid];
        }
    }
    __syncthreads();

    const int wvz   = wv * 528;
    const int b_loc = lane & 15;
    const int quad  = lane >> 4;
    float cst[2] = {0.f, 0.f};

    for (int t = 0; t < T_; ++t) {
        const int sw = t % DEPTH;
        const int sr = (t + DEPTH - 1) % DEPTH;
        const unsigned pI = (unsigned)((t / DEPTH) & 1);          // parity written at t
        const unsigned pO = (unsigned)(((t - 1) / DEPTH) & 1);    // parity of h[t-1] slot

        // x prefetch (L0), independent of sync
        float x0, x1, x2;
        if (layer == 0) {
            const size_t xb = (size_t)(wv * 16 + b_loc) * T_ + t;
            x0 = x[xb * 3 + 0]; x1 = x[xb * 3 + 1]; x2 = x[xb * 3 + 2];
        }

        // ---- input-edge flag waits + lagged anti-overwrite (R5 scheme) ----
        if (lane == 0) {
            if (layer == 0) {
                if (wv == 0 && t >= DEPTH) waitflag(F1 + ((t - DEPTH) * CP + cpi) * 32, 100);
            } else if (layer == 1) {
                waitflag(F0 + (t * CP + cpi) * 32, 50);
                if (wv == 0 && t >= DEPTH) waitflag(F2 + ((t - DEPTH) * CP + cpi) * 32, 100);
            } else if (layer == 2) {
                waitflag(F1 + (t * CP + cpi) * 32, 100);
                if (wv == 0 && t >= DEPTH) waitflag(FO + ((t - DEPTH) * CP + cpi) * 32, 1);
            } else {
                waitflag(F2 + (t * CP + cpi) * 32, 100);
            }
        }
        asm volatile("" ::: "memory");

        // input-edge loads (in flight while the own-edge poll spins)
        AFrag ainp[13];
        if (layer == 1 || layer == 2) {
            const unsigned* frI = frag0 + (size_t)((layer - 1) * DEPTH + sw) * FR_LS + wv * 3328;
#pragma unroll
            for (int kc = 0; kc < 13; ++kc)
#pragma unroll
                for (int d = 0; d < 4; ++d)
                    ainp[kc].u[d] = agloadu(frI + kc * 256 + d * 64 + lane);
        }

        // own-edge: parity-tagged data poll (the critical cycle)
        AFrag aown[13];
        if (layer == 3) {
            const unsigned* frI = frag0 + (size_t)(2 * DEPTH + sw) * FR_LS + wv * 3328;
#pragma unroll
            for (int kc = 0; kc < 13; ++kc)
#pragma unroll
                for (int d = 0; d < 4; ++d)
                    aown[kc].u[d] = agloadu(frI + kc * 256 + d * 64 + lane);
        } else if (t >= 1) {
            const unsigned* frO = frag0 + (size_t)(layer * DEPTH + sr) * FR_LS + wv * 3328;
            pollfrag13(frO, pO, aown, lane);
        } else {
#pragma unroll
            for (int kc = 0; kc < 13; ++kc)
#pragma unroll
                for (int d = 0; d < 4; ++d) aown[kc].u[d] = 0u;
        }
        asm volatile("" ::: "memory");

        // ---- MFMA ----
        if (layer == 0) {
            float4v acc0 = {0.f, 0.f, 0.f, 0.f}, acc1 = {0.f, 0.f, 0.f, 0.f};
#pragma unroll
            for (int kc = 0; kc < 13; ++kc) {
                const half8 w0 = *(const half8*)&wlds[kc * 512 + lane * 8];
                const half8 w1 = *(const half8*)&wlds[(13 + kc) * 512 + lane * 8];
                acc0 = __builtin_amdgcn_mfma_f32_16x16x32_f16(aown[kc].h, w0, acc0, 0, 0, 0);
                acc1 = __builtin_amdgcn_mfma_f32_16x16x32_f16(aown[kc].h, w1, acc1, 0, 0, 0);
            }
#pragma unroll
            for (int r = 0; r < 4; ++r) {
                zlds[wvz + (quad * 4 + r) * 33 + b_loc] = acc0[r];
                zlds[wvz + (quad * 4 + r) * 33 + 16 + b_loc] = acc1[r];
            }
        } else if (layer < 3) {
            float4v acc = {0.f, 0.f, 0.f, 0.f};
#pragma unroll
            for (int kc = 0; kc < 13; ++kc) {
                const half8 wA = *(const half8*)&wlds[kc * 512 + lane * 8];          // Wx part
                const half8 wB = *(const half8*)&wlds[(13 + kc) * 512 + lane * 8];   // Wh part
                acc = __builtin_amdgcn_mfma_f32_16x16x32_f16(ainp[kc].h, wA, acc, 0, 0, 0);
                acc = __builtin_amdgcn_mfma_f32_16x16x32_f16(aown[kc].h, wB, acc, 0, 0, 0);
            }
#pragma unroll
            for (int r = 0; r < 4; ++r)
                zlds[wvz + (quad * 4 + r) * 33 + b_loc] = acc[r];
        } else {
            float4v acc = {0.f, 0.f, 0.f, 0.f};
#pragma unroll
            for (int kc = 0; kc < 13; ++kc) {
                const half8 w0 = *(const half8*)&wlds[kc * 512 + lane * 8];
                acc = __builtin_amdgcn_mfma_f32_16x16x32_f16(aown[kc].h, w0, acc, 0, 0, 0);
            }
            if (b_loc < 3) {
#pragma unroll
                for (int r = 0; r < 4; ++r)
                    out[((size_t)(wv * 16 + quad * 4 + r) * T_ + t) * 3 + b_loc] = acc[r] + gc[b_loc];
            }
        }
        __syncthreads();   // zlds ready; also orders the lagged waits before stores

        // ---- K-pad rewrite (designated block per layer): parity-correct, non-NaN ----
        if (padw) {
            unsigned* fr_dst = frag0 + (size_t)(layer * DEPTH + sw) * FR_LS;
            agstoreu(fr_dst + pad_off[0], pI);
            agstoreu(fr_dst + pad_off[1], pI);
        }

        // ---- gates (fp32) + parity-tagged h store in A-fragment layout ----
        if (layer == 0) {
            unsigned* fr_dst = frag0 + (size_t)(0 * DEPTH + sw) * FR_LS + wv * 3328;
#pragma unroll
            for (int q = 0; q < 2; ++q) {
                const int ul = q * 4 + quad;
                const int ug = u0 + ul;
                float z[4];
#pragma unroll
                for (int g = 0; g < 4; ++g) {
                    const int gb = (g * 8 + ul) * 4;
                    z[g] = zlds[wvz + b_loc * 33 + g * 8 + ul]
                         + gc[gb + 0] + x0 * gc[gb + 1] + x1 * gc[gb + 2] + x2 * gc[gb + 3];
                }
                const float cp = cst[q];
                const float ig = sig_(z[0] + gc[128 + ul * 3 + 0] * cp);
                const float fg = sig_(z[1] + gc[128 + ul * 3 + 1] * cp);
                const float cn = fg * cp + ig * tanh_(z[2]);
                const float og = sig_(z[3] + gc[128 + ul * 3 + 2] * cn);
                cst[q] = cn;
                const float hv = og * tanh_(cn);
                const float pv = __shfl_xor(hv, 16, 64);
                if ((quad & 1) == 0) {
                    const unsigned pw_ = ((f16u(hv) & ~1u) | pI) | (f16u(pv) << 16);
                    const int u = ug;                    // even
                    agstoreu(fr_dst + (u >> 5) * 256 + ((u & 7) >> 1) * 64
                                    + ((u >> 3) & 3) * 16 + b_loc, pw_);
                }
            }
        } else if (layer < 3) {
            unsigned* fr_dst = frag0 + (size_t)(layer * DEPTH + sw) * FR_LS + wv * 3328;
            const int ul = quad;
            float z[4];
#pragma unroll
            for (int g = 0; g < 4; ++g)
                z[g] = zlds[wvz + b_loc * 33 + g * 4 + ul] + gc[g * 4 + ul];
            const float cp = cst[0];
            const float ig = sig_(z[0] + gc[16 + ul * 3 + 0] * cp);
            const float fg = sig_(z[1] + gc[16 + ul * 3 + 1] * cp);
            const float cn = fg * cp + ig * tanh_(z[2]);
            const float og = sig_(z[3] + gc[16 + ul * 3 + 2] * cn);
            cst[0] = cn;
            const float hv = og * tanh_(cn);
            const float pv = __shfl_xor(hv, 16, 64);
            if ((ul & 1) == 0) {
                const unsigned pw_ = ((f16u(hv) & ~1u) | pI) | (f16u(pv) << 16);
                const int u = u0 + ul;                   // even
                agstoreu(fr_dst + (u >> 5) * 256 + ((u & 7) >> 1) * 64
                                + ((u >> 3) & 3) * 16 + b_loc, pw_);
            }
        }

        // ---- publish flags (input edge + anti-overwrite consumers only) ----
        asm volatile("s_waitcnt vmcnt(0)" ::: "memory");
        __syncthreads();
        if (tid < CP) {
            unsigned* f = (layer == 0) ? F0 : (layer == 1) ? F1
                        : (layer == 2) ? F2 : FO;
            __hip_atomic_fetch_add(f + (t * CP + tid) * 32, 1u,
                                   __ATOMIC_RELAXED, __HIP_MEMORY_SCOPE_AGENT);
        }
    }
}

template<int DEPTH, int CP>
static void launch_variant(void* const* d_in, float* out, unsigned* ws, hipStream_t stream) {
    const float* x    = (const float*)d_in[0];
    const float* Wx0  = (const float*)d_in[1];
    const float* Wx1  = (const float*)d_in[2];
    const float* Wx2  = (const float*)d_in[3];
    const float* Wh   = (const float*)d_in[4];
    const float* bias = (const float*)d_in[5];
    const float* pi   = (const float*)d_in[6];
    const float* pf   = (const float*)d_in[7];
    const float* po   = (const float*)d_in[8];
    const float* Wd   = (const float*)d_in[9];
    const float* bd   = (const float*)d_in[10];
    void* args[] = { (void*)&x, (void*)&Wx0, (void*)&Wx1, (void*)&Wx2, (void*)&Wh,
                     (void*)&bias, (void*)&pi, (void*)&pf, (void*)&po,
                     (void*)&Wd, (void*)&bd, (void*)&out, (void*)&ws };
    hipError_t err = hipLaunchCooperativeKernel((void*)lstm_mix<DEPTH, CP>,
                                                dim3(251), dim3(256), args, 0, stream);
    if (err != hipSuccess)
        hipLaunchKernelGGL((lstm_mix<DEPTH, CP>), dim3(251), dim3(256), 0, stream,
                           x, Wx0, Wx1, Wx2, Wh, bias, pi, pf, po, Wd, bd, out, ws);
}

extern "C" void kernel_launch(void* const* d_in, const int* in_sizes, int n_in,
                              void* d_out, int out_size, void* d_ws, size_t ws_size,
                              hipStream_t stream) {
    float* out = (float*)d_out;
    unsigned* ws = (unsigned*)d_ws;

    auto flagbytes = [](int cp) -> size_t { return (size_t)4 * NF * cp * 32 * 4; };
    auto fragbytes = [](int depth) -> size_t { return (size_t)3 * depth * FR_LS * 4; };

    if (ws_size >= flagbytes(8) + fragbytes(8)) {          // ~4.2 MB
        hipMemsetAsync(d_ws, 0, flagbytes(8), stream);                          // flags = 0
        hipMemsetAsync((char*)d_ws + flagbytes(8), 0xFF, fragbytes(8), stream); // frags: parity-1
        launch_variant<8, 8>(d_in, out, ws, stream);
    } else if (ws_size >= flagbytes(4) + fragbytes(4)) {   // ~2.1 MB
        hipMemsetAsync(d_ws, 0, flagbytes(4), stream);
        hipMemsetAsync((char*)d_ws + flagbytes(4), 0xFF, fragbytes(4), stream);
        launch_variant<4, 4>(d_in, out, ws, stream);
    } else {                                                // ~1.0 MB
        hipMemsetAsync(d_ws, 0, flagbytes(2), stream);
        hipMemsetAsync((char*)d_ws + flagbytes(2), 0xFF, fragbytes(2), stream);
        launch_variant<2, 2>(d_in, out, ws, stream);
    }
}